// Round 6
// baseline (373.978 us; speedup 1.0000x reference)
//
#include <hip/hip_runtime.h>

typedef __attribute__((ext_vector_type(4))) float f32x4;
typedef __attribute__((ext_vector_type(8))) short short8;
typedef __attribute__((ext_vector_type(8))) unsigned short u16x8;
typedef __attribute__((ext_vector_type(4))) unsigned short u16x4;

#define D_MODEL 1024
#define NHEADS 16
#define T_SEQ 2048
#define M_TOT 4096   // B*T

__device__ __forceinline__ unsigned short f2bf(float f) {
    union { float f; unsigned int u; } v; v.f = f;
    return (unsigned short)((v.u + 0x7fffu + ((v.u >> 16) & 1u)) >> 16);
}

// ---- 16-lane group all-reduce at VALU speed (DPP), shfl fallback (proven in R5) ----
#if __has_builtin(__builtin_amdgcn_update_dpp)
#define DPP_STEP(v, ctrl, OP)                                              \
    {                                                                      \
        union { float f; int i; } a_, b_;                                  \
        a_.f = (v);                                                        \
        b_.i = __builtin_amdgcn_update_dpp(a_.i, a_.i, ctrl, 0xf, 0xf, false); \
        (v) = OP((v), b_.f);                                               \
    }
__device__ __forceinline__ float rowmax16(float v) {
    DPP_STEP(v, 0xB1, fmaxf); DPP_STEP(v, 0x4E, fmaxf);
    DPP_STEP(v, 0x141, fmaxf); DPP_STEP(v, 0x140, fmaxf);
    return v;
}
__device__ __forceinline__ float rowsum16(float v) {
    #define FADD_(a, b) ((a) + (b))
    DPP_STEP(v, 0xB1, FADD_); DPP_STEP(v, 0x4E, FADD_);
    DPP_STEP(v, 0x141, FADD_); DPP_STEP(v, 0x140, FADD_);
    #undef FADD_
    return v;
}
#else
__device__ __forceinline__ float rowmax16(float v) {
    for (int off = 8; off >= 1; off >>= 1) v = fmaxf(v, __shfl_xor(v, off));
    return v;
}
__device__ __forceinline__ float rowsum16(float v) {
    for (int off = 8; off >= 1; off >>= 1) v += __shfl_xor(v, off);
    return v;
}
#endif

// ---------------- convert x fp32 -> bf16 ----------------
__global__ __launch_bounds__(256) void convert_x_kernel(const float* __restrict__ X,
                                                        unsigned short* __restrict__ Xb) {
    const int i = (blockIdx.x * 256 + threadIdx.x) * 4;
    const float4 v = *(const float4*)(X + i);
    u16x4 r;
    r.x = f2bf(v.x); r.y = f2bf(v.y); r.z = f2bf(v.z); r.w = f2bf(v.w);
    *(u16x4*)(Xb + i) = r;
}

// ---------------- 4x W [k][n] fp32 -> Wt [n][k] bf16, batched over z ----------------
__global__ __launch_bounds__(256) void transpose_w_kernel(const float* __restrict__ W0,
                                                          const float* __restrict__ W1,
                                                          const float* __restrict__ W2,
                                                          const float* __restrict__ W3,
                                                          unsigned short* __restrict__ Wt0) {
    __shared__ float tile[64][65];
    const int z = blockIdx.z;
    const float* W = (z == 0) ? W0 : (z == 1) ? W1 : (z == 2) ? W2 : W3;
    unsigned short* Wt = Wt0 + (size_t)z * D_MODEL * D_MODEL;
    const int n0 = blockIdx.x * 64, k0 = blockIdx.y * 64;
    for (int i = threadIdx.x; i < 4096; i += 256) {
        const int r = i >> 6, c = i & 63;
        tile[r][c] = W[(size_t)(k0 + r) * D_MODEL + n0 + c];
    }
    __syncthreads();
    for (int i = threadIdx.x; i < 4096; i += 256) {
        const int r = i >> 6, c = i & 63;  // r: n-local, c: k-local
        Wt[(size_t)(n0 + r) * D_MODEL + k0 + c] = f2bf(tile[c][r]);
    }
}

// ---------------- GEMM: C = A[M][1024] @ W, with Wt[n][k] pre-transposed ----------------
// OUTMODE 0: fp32 row-major C (out projection)
// OUTMODE 1: z=0 Q (RoPE, pre-scaled 0.125), z=1 K (RoPE), z=2 V (transposed [bh][d][t])
#define TN_G 128
#define BK_G 32
#define BKP_G 36

template<int MI, int OUTMODE>
__global__ __launch_bounds__(256) void gemm_kernel(
    const unsigned short* __restrict__ A,
    const unsigned short* __restrict__ Bt0,
    void* __restrict__ Cout0,
    const float* __restrict__ cosp,
    const float* __restrict__ sinp)
{
    constexpr int TMc = MI * 32;
    constexpr int NA = (TMc * 4) / 256;
    __shared__ unsigned short sA[TMc * BKP_G];
    __shared__ unsigned short sB[TN_G * BKP_G];

    const int tid = threadIdx.x;
    const int wid = tid >> 6;
    const int lane = tid & 63;
    const int quad = lane >> 4;
    const int l16 = lane & 15;
    const int wm = wid >> 1, wn = wid & 1;
    const int m0 = blockIdx.x * TMc, n0 = blockIdx.y * TN_G;
    const int z = blockIdx.z;
    const unsigned short* Bt = Bt0 + (size_t)z * D_MODEL * D_MODEL;

    f32x4 acc[MI][4] = {};

    for (int k0 = 0; k0 < D_MODEL; k0 += BK_G) {
        u16x8 av[NA], bv[2];
        #pragma unroll
        for (int i = 0; i < NA; ++i) {
            const int c = tid + i * 256, r = c >> 2, sg = (c & 3) * 8;
            av[i] = *(const u16x8*)(A + (size_t)(m0 + r) * D_MODEL + k0 + sg);
        }
        #pragma unroll
        for (int i = 0; i < 2; ++i) {
            const int c = tid + i * 256, r = c >> 2, sg = (c & 3) * 8;
            bv[i] = *(const u16x8*)(Bt + (size_t)(n0 + r) * D_MODEL + k0 + sg);
        }
        __syncthreads();
        #pragma unroll
        for (int i = 0; i < NA; ++i) {
            const int c = tid + i * 256, r = c >> 2, sg = (c & 3) * 8;
            *(u16x8*)&sA[r * BKP_G + sg] = av[i];
        }
        #pragma unroll
        for (int i = 0; i < 2; ++i) {
            const int c = tid + i * 256, r = c >> 2, sg = (c & 3) * 8;
            *(u16x8*)&sB[r * BKP_G + sg] = bv[i];
        }
        __syncthreads();

        short8 af[MI], bf[4];
        #pragma unroll
        for (int i = 0; i < MI; ++i)
            af[i] = *(const short8*)&sA[(wm * (MI * 16) + i * 16 + l16) * BKP_G + quad * 8];
        #pragma unroll
        for (int i = 0; i < 4; ++i)
            bf[i] = *(const short8*)&sB[(wn * 64 + i * 16 + l16) * BKP_G + quad * 8];
        #pragma unroll
        for (int mi = 0; mi < MI; ++mi)
            #pragma unroll
            for (int ni = 0; ni < 4; ++ni)
                acc[mi][ni] = __builtin_amdgcn_mfma_f32_16x16x32_bf16(af[mi], bf[ni], acc[mi][ni], 0, 0, 0);
    }

    if constexpr (OUTMODE == 0) {
        float* C = (float*)Cout0;
        #pragma unroll
        for (int mi = 0; mi < MI; ++mi) {
            const int mb = m0 + wm * (MI * 16) + mi * 16 + quad * 4;
            #pragma unroll
            for (int ni = 0; ni < 4; ++ni) {
                const int n = n0 + wn * 64 + ni * 16 + l16;
                #pragma unroll
                for (int r = 0; r < 4; ++r)
                    C[(size_t)(mb + r) * D_MODEL + n] = acc[mi][ni][r];
            }
        }
    } else {
        unsigned short* O = (unsigned short*)Cout0 + (size_t)z * M_TOT * D_MODEL;
        const int h = (n0 + wn * 64) >> 6;   // each wave's 64 cols = exactly one head
        if (z == 2) {
            // V: write transposed Vt[bh][d][t], packed u16x4 over 4 consecutive t
            #pragma unroll
            for (int mi = 0; mi < MI; ++mi) {
                const int mb = m0 + wm * (MI * 16) + mi * 16 + quad * 4;
                const int b = mb >> 11, t = mb & (T_SEQ - 1);
                #pragma unroll
                for (int ni = 0; ni < 4; ++ni) {
                    const int d = ni * 16 + l16;
                    u16x4 pk;
                    #pragma unroll
                    for (int r = 0; r < 4; ++r) pk[r] = f2bf(acc[mi][ni][r]);
                    *(u16x4*)(O + ((size_t)(b * NHEADS + h) * 64 + d) * T_SEQ + t) = pk;
                }
            }
        } else {
            const float qs = (z == 0) ? 0.125f : 1.0f;   // fold 1/sqrt(64) into Q (exact in bf16)
            #pragma unroll
            for (int mi = 0; mi < MI; ++mi) {
                #pragma unroll
                for (int r = 0; r < 4; ++r) {
                    const int m = m0 + wm * (MI * 16) + mi * 16 + quad * 4 + r;
                    const int b = m >> 11, t = m & (T_SEQ - 1);
                    const size_t rowoff = ((size_t)(b * NHEADS + h) * T_SEQ + t) * 64;
                    #pragma unroll
                    for (int ni = 0; ni < 2; ++ni) {
                        const int d = ni * 16 + l16;           // 0..31
                        const float c = cosp[t * 32 + d], s = sinp[t * 32 + d];
                        const float x1 = acc[mi][ni][r], x2 = acc[mi][ni + 2][r];
                        O[rowoff + d]      = f2bf((x1 * c - x2 * s) * qs);
                        O[rowoff + d + 32] = f2bf((x1 * s + x2 * c) * qs);
                    }
                }
            }
        }
    }
}

// ---------------- flash attention (causal): TWO-PASS exact-max softmax ----------------
// Pass 1: stream K only, QK + per-lane register max (no cross-lane, no LDS P, no V).
// One rowmax16 after -> exact row max m. Pass 2: stream K+V, p = exp2(s*log2e - m*log2e)
// <= 1 always (provably overflow-free), per-lane l partials, P->LDS->PV. No loop-carried
// chain in either pass.
#define LDA 66   // K/V LDS row pad (u16): b128 frag reads 2-way max (free)
#define LDP 68   // P LDS row pad (u16): scalar P writes conflict-free
#define LOG2E 1.44269504f

__global__ __launch_bounds__(256) void attn_kernel(
    const unsigned short* __restrict__ Q,    // [bh][t][64] bf16, RoPE'd, pre-scaled 0.125
    const unsigned short* __restrict__ Kg,   // [bh][t][64] bf16, RoPE'd
    const unsigned short* __restrict__ Vt,   // [bh][d][t]  bf16 (transposed)
    unsigned short* __restrict__ Z)          // [m][h*64+d] bf16
{
    __shared__ unsigned short sK[2][64 * LDA];
    __shared__ unsigned short sV[2][64 * LDA];
    __shared__ unsigned short sP[4][2][16 * LDP];

    const int tid = threadIdx.x;
    const int wid = tid >> 6;
    const int lane = tid & 63;
    const int quad = lane >> 4;
    const int l16 = lane & 15;
    const int x = blockIdx.x;            // 0..15
    const int bh = blockIdx.y;           // 0..31
    const int qA = x, qB = 31 - x;       // paired q-tiles: work = 32-x, near-uniform
    const int jend = 31 - x;             // kv tiles 0..jend cover both

    const unsigned short* Qp = Q + (size_t)bh * T_SEQ * 64;
    const unsigned short* Kp = Kg + (size_t)bh * T_SEQ * 64;
    const unsigned short* Vp = Vt + (size_t)bh * 64 * T_SEQ;

    // Q A-frags: row = qt*64 + wid*16 + l16, k = ks*32 + quad*8
    short8 aqA[2], aqB[2];
    {
        const unsigned short* qr = Qp + (size_t)(qA * 64 + wid * 16 + l16) * 64 + quad * 8;
        aqA[0] = *(const short8*)(qr);
        aqA[1] = *(const short8*)(qr + 32);
        qr = Qp + (size_t)(qB * 64 + wid * 16 + l16) * 64 + quad * 8;
        aqB[0] = *(const short8*)(qr);
        aqB[1] = *(const short8*)(qr + 32);
    }

    // staging
    const int sr0 = tid >> 3, scol0 = (tid & 7) * 8;   // rows 0..31
    const int sr1 = sr0 + 32;                          // rows 32..63
    u16x8 kreg0, kreg1, vreg0, vreg1;

    auto load_k = [&](int j) {
        const unsigned short* Ks = Kp + (size_t)(j * 64) * 64;
        kreg0 = *(const u16x8*)(Ks + sr0 * 64 + scol0);
        kreg1 = *(const u16x8*)(Ks + sr1 * 64 + scol0);
    };
    auto store_k = [&](int p) {
        *(u16x8*)&sK[p][sr0 * LDA + scol0] = kreg0;
        *(u16x8*)&sK[p][sr1 * LDA + scol0] = kreg1;
    };
    auto load_v = [&](int j) {
        vreg0 = *(const u16x8*)(Vp + (size_t)sr0 * T_SEQ + j * 64 + scol0);
        vreg1 = *(const u16x8*)(Vp + (size_t)sr1 * T_SEQ + j * 64 + scol0);
    };
    auto store_v = [&](int p) {
        *(u16x8*)&sV[p][sr0 * LDA + scol0] = vreg0;
        *(u16x8*)&sV[p][sr1 * LDA + scol0] = vreg1;
    };

    auto qk_tiles = [&](const unsigned short* bK, f32x4 (&sAc)[4], f32x4 (&sBc)[4], bool doA) {
        #pragma unroll
        for (int nt = 0; nt < 4; ++nt) {
            const short8 kf0 = *(const short8*)&bK[(nt * 16 + l16) * LDA + quad * 8];
            const short8 kf1 = *(const short8*)&bK[(nt * 16 + l16) * LDA + 32 + quad * 8];
            if (doA) {
                sAc[nt] = __builtin_amdgcn_mfma_f32_16x16x32_bf16(aqA[0], kf0, sAc[nt], 0, 0, 0);
                sAc[nt] = __builtin_amdgcn_mfma_f32_16x16x32_bf16(aqA[1], kf1, sAc[nt], 0, 0, 0);
            }
            sBc[nt] = __builtin_amdgcn_mfma_f32_16x16x32_bf16(aqB[0], kf0, sBc[nt], 0, 0, 0);
            sBc[nt] = __builtin_amdgcn_mfma_f32_16x16x32_bf16(aqB[1], kf1, sBc[nt], 0, 0, 0);
        }
    };
    auto mask_tile = [&](f32x4 (&s)[4]) {   // causal mask on the diagonal 64x64 tile
        #pragma unroll
        for (int nt = 0; nt < 4; ++nt) {
            const int col = nt * 16 + l16;
            #pragma unroll
            for (int r = 0; r < 4; ++r) {
                const int row = wid * 16 + quad * 4 + r;
                if (col > row) s[nt][r] = -1e30f;
            }
        }
    };

    // ================= pass 1: exact row max (K only) =================
    float mA[4] = {-1e30f, -1e30f, -1e30f, -1e30f};
    float mB[4] = {-1e30f, -1e30f, -1e30f, -1e30f};

    load_k(0);
    store_k(0);
    __syncthreads();
    for (int j = 0; j <= jend; ++j) {
        const int p = j & 1;
        if (j < jend) load_k(j + 1);
        const bool doA = (j <= x);
        f32x4 sAc[4] = {}, sBc[4] = {};
        qk_tiles(&sK[p][0], sAc, sBc, doA);
        if (doA) {
            if (j == x) mask_tile(sAc);
            #pragma unroll
            for (int r = 0; r < 4; ++r)
                mA[r] = fmaxf(mA[r], fmaxf(fmaxf(sAc[0][r], sAc[1][r]), fmaxf(sAc[2][r], sAc[3][r])));
        }
        if (j == jend) mask_tile(sBc);
        #pragma unroll
        for (int r = 0; r < 4; ++r)
            mB[r] = fmaxf(mB[r], fmaxf(fmaxf(sBc[0][r], sBc[1][r]), fmaxf(sBc[2][r], sBc[3][r])));
        if (j < jend) store_k(1 - p);
        __syncthreads();
    }
    // exact max across the 16-lane row group; pre-scale by log2(e) for exp2
    float mLA[4], mLB[4];
    #pragma unroll
    for (int r = 0; r < 4; ++r) {
        mLA[r] = rowmax16(mA[r]) * LOG2E;
        mLB[r] = rowmax16(mB[r]) * LOG2E;
    }

    // ================= pass 2: fixed-max softmax + PV =================
    f32x4 oA[4] = {}, oB[4] = {};
    float lA[4] = {0.f, 0.f, 0.f, 0.f}, lB[4] = {0.f, 0.f, 0.f, 0.f};

    // p = exp2(s*log2e - mL): <= 1 by construction. Mask forces s to -1e30 first -> p = 0.
    auto tile_exp = [&](f32x4 (&s)[4], const float (&mL)[4], float (&l_i)[4], bool msk,
                        unsigned short* Pw) {
        if (msk) mask_tile(s);
        #pragma unroll
        for (int nt = 0; nt < 4; ++nt) {
            const int col = nt * 16 + l16;
            #pragma unroll
            for (int r = 0; r < 4; ++r) {
                const float p = __builtin_exp2f(s[nt][r] * LOG2E - mL[r]);
                l_i[r] += p;
                Pw[(quad * 4 + r) * LDP + col] = f2bf(p);
            }
        }
    };

    load_k(0); load_v(0);
    store_k(0); store_v(0);
    __syncthreads();
    for (int j = 0; j <= jend; ++j) {
        const int p = j & 1;
        if (j < jend) { load_k(j + 1); load_v(j + 1); }
        const bool doA = (j <= x);
        const unsigned short* bV = &sV[p][0];

        f32x4 sAc[4] = {}, sBc[4] = {};
        qk_tiles(&sK[p][0], sAc, sBc, doA);

        unsigned short* PwA = &sP[wid][0][0];
        unsigned short* PwB = &sP[wid][1][0];
        if (doA) tile_exp(sAc, mLA, lA, j == x, PwA);
        tile_exp(sBc, mLB, lB, j == jend, PwB);
        asm volatile("s_waitcnt lgkmcnt(0)" ::: "memory");

        short8 pfA0 = {}, pfA1 = {}, pfB0, pfB1;
        if (doA) {
            pfA0 = *(const short8*)&PwA[l16 * LDP + quad * 8];
            pfA1 = *(const short8*)&PwA[l16 * LDP + 32 + quad * 8];
        }
        pfB0 = *(const short8*)&PwB[l16 * LDP + quad * 8];
        pfB1 = *(const short8*)&PwB[l16 * LDP + 32 + quad * 8];

        // O += P @ V  (V frags shared between tiles)
        #pragma unroll
        for (int dt = 0; dt < 4; ++dt) {
            const short8 vf0 = *(const short8*)&bV[(dt * 16 + l16) * LDA + quad * 8];
            const short8 vf1 = *(const short8*)&bV[(dt * 16 + l16) * LDA + 32 + quad * 8];
            if (doA) {
                oA[dt] = __builtin_amdgcn_mfma_f32_16x16x32_bf16(pfA0, vf0, oA[dt], 0, 0, 0);
                oA[dt] = __builtin_amdgcn_mfma_f32_16x16x32_bf16(pfA1, vf1, oA[dt], 0, 0, 0);
            }
            oB[dt] = __builtin_amdgcn_mfma_f32_16x16x32_bf16(pfB0, vf0, oB[dt], 0, 0, 0);
            oB[dt] = __builtin_amdgcn_mfma_f32_16x16x32_bf16(pfB1, vf1, oB[dt], 0, 0, 0);
        }

        if (j < jend) { store_k(1 - p); store_v(1 - p); }
        __syncthreads();
    }

    // single cross-lane row-sum of the per-lane l partials
    #pragma unroll
    for (int r = 0; r < 4; ++r) {
        lA[r] = 1.f / rowsum16(lA[r]);
        lB[r] = 1.f / rowsum16(lB[r]);
    }

    // epilogue: normalize and write
    const int h = bh & 15, b = bh >> 4;
    #pragma unroll
    for (int dt = 0; dt < 4; ++dt)
        #pragma unroll
        for (int r = 0; r < 4; ++r) {
            const int rowA = qA * 64 + wid * 16 + quad * 4 + r;
            const int rowB = qB * 64 + wid * 16 + quad * 4 + r;
            const int col = h * 64 + dt * 16 + l16;
            Z[((size_t)b * T_SEQ + rowA) * D_MODEL + col] = f2bf(oA[dt][r] * lA[r]);
            Z[((size_t)b * T_SEQ + rowB) * D_MODEL + col] = f2bf(oB[dt][r] * lB[r]);
        }
}

// ---------------- launcher ----------------
extern "C" void kernel_launch(void* const* d_in, const int* in_sizes, int n_in,
                              void* d_out, int out_size, void* d_ws, size_t ws_size,
                              hipStream_t stream) {
    const float* x    = (const float*)d_in[0];
    const float* cosp = (const float*)d_in[1];
    const float* sinp = (const float*)d_in[2];
    const float* Wq   = (const float*)d_in[3];
    const float* Wk   = (const float*)d_in[4];
    const float* Wv   = (const float*)d_in[5];
    const float* Wo   = (const float*)d_in[6];

    char* w = (char*)d_ws;
    unsigned short* xb  = (unsigned short*)w; w += (size_t)M_TOT * D_MODEL * 2;    // 8 MB
    unsigned short* wt  = (unsigned short*)w; w += (size_t)4 * D_MODEL * D_MODEL * 2; // 8 MB (q,k,v,o)
    unsigned short* Qb  = (unsigned short*)w; w += (size_t)M_TOT * D_MODEL * 2;    // 8 MB
    unsigned short* Kb  = (unsigned short*)w; w += (size_t)M_TOT * D_MODEL * 2;
    unsigned short* Vtb = (unsigned short*)w; w += (size_t)M_TOT * D_MODEL * 2;    // [bh][d][t]
    unsigned short* Zb  = (unsigned short*)w; w += (size_t)M_TOT * D_MODEL * 2;

    convert_x_kernel<<<(M_TOT * D_MODEL) / 1024, 256, 0, stream>>>(x, xb);
    transpose_w_kernel<<<dim3(16, 16, 4), 256, 0, stream>>>(Wq, Wk, Wv, Wo, wt);

    // fused QKV projection; epilogue: z=0 Q(RoPE,*0.125), z=1 K(RoPE), z=2 V(transposed)
    gemm_kernel<4, 1><<<dim3(M_TOT / 128, D_MODEL / 128, 3), 256, 0, stream>>>(
        xb, wt, (void*)Qb, cosp, sinp);

    attn_kernel<<<dim3(16, 32), 256, 0, stream>>>(Qb, Kb, Vtb, Zb);

    // out projection -> fp32 d_out
    gemm_kernel<2, 0><<<dim3(M_TOT / 64, D_MODEL / 128, 1), 256, 0, stream>>>(
        Zb, wt + (size_t)3 * D_MODEL * D_MODEL, d_out, nullptr, nullptr);
}

// Round 7
// 334.128 us; speedup vs baseline: 1.1193x; 1.1193x over previous
//
#include <hip/hip_runtime.h>

typedef __attribute__((ext_vector_type(4))) float f32x4;
typedef __attribute__((ext_vector_type(8))) short short8;
typedef __attribute__((ext_vector_type(8))) unsigned short u16x8;
typedef __attribute__((ext_vector_type(4))) unsigned short u16x4;

#define D_MODEL 1024
#define NHEADS 16
#define T_SEQ 2048
#define M_TOT 4096   // B*T

__device__ __forceinline__ unsigned short f2bf(float f) {
    union { float f; unsigned int u; } v; v.f = f;
    return (unsigned short)((v.u + 0x7fffu + ((v.u >> 16) & 1u)) >> 16);
}

// ---- 16-lane group all-reduce at VALU speed (DPP), shfl fallback (proven in R5) ----
#if __has_builtin(__builtin_amdgcn_update_dpp)
#define DPP_STEP(v, ctrl, OP)                                              \
    {                                                                      \
        union { float f; int i; } a_, b_;                                  \
        a_.f = (v);                                                        \
        b_.i = __builtin_amdgcn_update_dpp(a_.i, a_.i, ctrl, 0xf, 0xf, false); \
        (v) = OP((v), b_.f);                                               \
    }
__device__ __forceinline__ float rowmax16(float v) {
    DPP_STEP(v, 0xB1, fmaxf); DPP_STEP(v, 0x4E, fmaxf);
    DPP_STEP(v, 0x141, fmaxf); DPP_STEP(v, 0x140, fmaxf);
    return v;
}
__device__ __forceinline__ float rowsum16(float v) {
    #define FADD_(a, b) ((a) + (b))
    DPP_STEP(v, 0xB1, FADD_); DPP_STEP(v, 0x4E, FADD_);
    DPP_STEP(v, 0x141, FADD_); DPP_STEP(v, 0x140, FADD_);
    #undef FADD_
    return v;
}
#else
__device__ __forceinline__ float rowmax16(float v) {
    for (int off = 8; off >= 1; off >>= 1) v = fmaxf(v, __shfl_xor(v, off));
    return v;
}
__device__ __forceinline__ float rowsum16(float v) {
    for (int off = 8; off >= 1; off >>= 1) v += __shfl_xor(v, off);
    return v;
}
#endif

// ---------------- convert x fp32 -> bf16 ----------------
__global__ __launch_bounds__(256) void convert_x_kernel(const float* __restrict__ X,
                                                        unsigned short* __restrict__ Xb) {
    const int i = (blockIdx.x * 256 + threadIdx.x) * 4;
    const float4 v = *(const float4*)(X + i);
    u16x4 r;
    r.x = f2bf(v.x); r.y = f2bf(v.y); r.z = f2bf(v.z); r.w = f2bf(v.w);
    *(u16x4*)(Xb + i) = r;
}

// ---------------- 4x W [k][n] fp32 -> Wt [n][k] bf16, batched over z ----------------
__global__ __launch_bounds__(256) void transpose_w_kernel(const float* __restrict__ W0,
                                                          const float* __restrict__ W1,
                                                          const float* __restrict__ W2,
                                                          const float* __restrict__ W3,
                                                          unsigned short* __restrict__ Wt0) {
    __shared__ float tile[64][65];
    const int z = blockIdx.z;
    const float* W = (z == 0) ? W0 : (z == 1) ? W1 : (z == 2) ? W2 : W3;
    unsigned short* Wt = Wt0 + (size_t)z * D_MODEL * D_MODEL;
    const int n0 = blockIdx.x * 64, k0 = blockIdx.y * 64;
    for (int i = threadIdx.x; i < 4096; i += 256) {
        const int r = i >> 6, c = i & 63;
        tile[r][c] = W[(size_t)(k0 + r) * D_MODEL + n0 + c];
    }
    __syncthreads();
    for (int i = threadIdx.x; i < 4096; i += 256) {
        const int r = i >> 6, c = i & 63;  // r: n-local, c: k-local
        Wt[(size_t)(n0 + r) * D_MODEL + k0 + c] = f2bf(tile[c][r]);
    }
}

// ---------------- GEMM: C = A[M][1024] @ W, with Wt[n][k] pre-transposed ----------------
// OUTMODE 0: fp32 row-major C (out projection)
// OUTMODE 1: z=0 Q (RoPE, pre-scaled 0.125), z=1 K (RoPE), z=2 V (transposed [bh][d][t])
#define TN_G 128
#define BK_G 32
#define BKP_G 36

template<int MI, int OUTMODE>
__global__ __launch_bounds__(256) void gemm_kernel(
    const unsigned short* __restrict__ A,
    const unsigned short* __restrict__ Bt0,
    void* __restrict__ Cout0,
    const float* __restrict__ cosp,
    const float* __restrict__ sinp)
{
    constexpr int TMc = MI * 32;
    constexpr int NA = (TMc * 4) / 256;
    __shared__ unsigned short sA[TMc * BKP_G];
    __shared__ unsigned short sB[TN_G * BKP_G];

    const int tid = threadIdx.x;
    const int wid = tid >> 6;
    const int lane = tid & 63;
    const int quad = lane >> 4;
    const int l16 = lane & 15;
    const int wm = wid >> 1, wn = wid & 1;
    const int m0 = blockIdx.x * TMc, n0 = blockIdx.y * TN_G;
    const int z = blockIdx.z;
    const unsigned short* Bt = Bt0 + (size_t)z * D_MODEL * D_MODEL;

    f32x4 acc[MI][4] = {};

    for (int k0 = 0; k0 < D_MODEL; k0 += BK_G) {
        u16x8 av[NA], bv[2];
        #pragma unroll
        for (int i = 0; i < NA; ++i) {
            const int c = tid + i * 256, r = c >> 2, sg = (c & 3) * 8;
            av[i] = *(const u16x8*)(A + (size_t)(m0 + r) * D_MODEL + k0 + sg);
        }
        #pragma unroll
        for (int i = 0; i < 2; ++i) {
            const int c = tid + i * 256, r = c >> 2, sg = (c & 3) * 8;
            bv[i] = *(const u16x8*)(Bt + (size_t)(n0 + r) * D_MODEL + k0 + sg);
        }
        __syncthreads();
        #pragma unroll
        for (int i = 0; i < NA; ++i) {
            const int c = tid + i * 256, r = c >> 2, sg = (c & 3) * 8;
            *(u16x8*)&sA[r * BKP_G + sg] = av[i];
        }
        #pragma unroll
        for (int i = 0; i < 2; ++i) {
            const int c = tid + i * 256, r = c >> 2, sg = (c & 3) * 8;
            *(u16x8*)&sB[r * BKP_G + sg] = bv[i];
        }
        __syncthreads();

        short8 af[MI], bf[4];
        #pragma unroll
        for (int i = 0; i < MI; ++i)
            af[i] = *(const short8*)&sA[(wm * (MI * 16) + i * 16 + l16) * BKP_G + quad * 8];
        #pragma unroll
        for (int i = 0; i < 4; ++i)
            bf[i] = *(const short8*)&sB[(wn * 64 + i * 16 + l16) * BKP_G + quad * 8];
        #pragma unroll
        for (int mi = 0; mi < MI; ++mi)
            #pragma unroll
            for (int ni = 0; ni < 4; ++ni)
                acc[mi][ni] = __builtin_amdgcn_mfma_f32_16x16x32_bf16(af[mi], bf[ni], acc[mi][ni], 0, 0, 0);
    }

    if constexpr (OUTMODE == 0) {
        float* C = (float*)Cout0;
        #pragma unroll
        for (int mi = 0; mi < MI; ++mi) {
            const int mb = m0 + wm * (MI * 16) + mi * 16 + quad * 4;
            #pragma unroll
            for (int ni = 0; ni < 4; ++ni) {
                const int n = n0 + wn * 64 + ni * 16 + l16;
                #pragma unroll
                for (int r = 0; r < 4; ++r)
                    C[(size_t)(mb + r) * D_MODEL + n] = acc[mi][ni][r];
            }
        }
    } else {
        unsigned short* O = (unsigned short*)Cout0 + (size_t)z * M_TOT * D_MODEL;
        const int h = (n0 + wn * 64) >> 6;   // each wave's 64 cols = exactly one head
        if (z == 2) {
            // V: write transposed Vt[bh][d][t], packed u16x4 over 4 consecutive t
            #pragma unroll
            for (int mi = 0; mi < MI; ++mi) {
                const int mb = m0 + wm * (MI * 16) + mi * 16 + quad * 4;
                const int b = mb >> 11, t = mb & (T_SEQ - 1);
                #pragma unroll
                for (int ni = 0; ni < 4; ++ni) {
                    const int d = ni * 16 + l16;
                    u16x4 pk;
                    #pragma unroll
                    for (int r = 0; r < 4; ++r) pk[r] = f2bf(acc[mi][ni][r]);
                    *(u16x4*)(O + ((size_t)(b * NHEADS + h) * 64 + d) * T_SEQ + t) = pk;
                }
            }
        } else {
            const float qs = (z == 0) ? 0.125f : 1.0f;   // fold 1/sqrt(64) into Q (exact in bf16)
            #pragma unroll
            for (int mi = 0; mi < MI; ++mi) {
                #pragma unroll
                for (int r = 0; r < 4; ++r) {
                    const int m = m0 + wm * (MI * 16) + mi * 16 + quad * 4 + r;
                    const int b = m >> 11, t = m & (T_SEQ - 1);
                    const size_t rowoff = ((size_t)(b * NHEADS + h) * T_SEQ + t) * 64;
                    #pragma unroll
                    for (int ni = 0; ni < 2; ++ni) {
                        const int d = ni * 16 + l16;           // 0..31
                        const float c = cosp[t * 32 + d], s = sinp[t * 32 + d];
                        const float x1 = acc[mi][ni][r], x2 = acc[mi][ni + 2][r];
                        O[rowoff + d]      = f2bf((x1 * c - x2 * s) * qs);
                        O[rowoff + d + 32] = f2bf((x1 * s + x2 * c) * qs);
                    }
                }
            }
        }
    }
}

// ---------------- flash attention (causal): BARRIER-FREE two-pass exact-max ----------------
// K and Vt MFMA fragments are loaded DIRECTLY from global to registers (each 64B line is
// fully consumed by the 4 quads of one l16 group -> 100% line utilization; K/V per head =
// 512 KB, L2-resident). Only LDS use: per-wave P round-trip (lgkm wait, no cross-wave dep).
// ZERO __syncthreads: no barrier convoy, no vmcnt drains; waves fully independent.
#define LDP 68   // P LDS row pad (u16): scalar P writes conflict-free
#define LOG2E 1.44269504f

__global__ __launch_bounds__(256) void attn_kernel(
    const unsigned short* __restrict__ Q,    // [bh][t][64] bf16, RoPE'd, pre-scaled 0.125
    const unsigned short* __restrict__ Kg,   // [bh][t][64] bf16, RoPE'd
    const unsigned short* __restrict__ Vt,   // [bh][d][t]  bf16 (transposed)
    unsigned short* __restrict__ Z)          // [m][h*64+d] bf16
{
    __shared__ unsigned short sP[4][2][16 * LDP];

    const int tid = threadIdx.x;
    const int wid = tid >> 6;
    const int lane = tid & 63;
    const int quad = lane >> 4;
    const int l16 = lane & 15;
    const int x = blockIdx.x;            // 0..15
    const int bh = blockIdx.y;           // 0..31
    const int qA = x, qB = 31 - x;       // paired q-tiles: work = 32-x, near-uniform
    const int jend = 31 - x;             // kv tiles 0..jend cover both

    const unsigned short* Qp = Q + (size_t)bh * T_SEQ * 64;
    const unsigned short* Kp = Kg + (size_t)bh * T_SEQ * 64;
    const unsigned short* Vp = Vt + (size_t)bh * 64 * T_SEQ;

    // Q A-frags: row = qt*64 + wid*16 + l16, k = ks*32 + quad*8
    short8 aqA[2], aqB[2];
    {
        const unsigned short* qr = Qp + (size_t)(qA * 64 + wid * 16 + l16) * 64 + quad * 8;
        aqA[0] = *(const short8*)(qr);
        aqA[1] = *(const short8*)(qr + 32);
        qr = Qp + (size_t)(qB * 64 + wid * 16 + l16) * 64 + quad * 8;
        aqB[0] = *(const short8*)(qr);
        aqB[1] = *(const short8*)(qr + 32);
    }

    // direct-from-global fragment base addresses (per lane)
    const unsigned short* Kfb = Kp + (size_t)l16 * 64 + quad * 8;        // + (j*64+nt*16)*64 + ks*32
    const unsigned short* Vfb = Vp + (size_t)l16 * T_SEQ + quad * 8;     // + dt*16*T_SEQ + j*64 + ks*32

    auto qk_tiles = [&](const short8 (&kf)[4][2], f32x4 (&sAc)[4], f32x4 (&sBc)[4], bool doA) {
        #pragma unroll
        for (int nt = 0; nt < 4; ++nt) {
            if (doA) {
                sAc[nt] = __builtin_amdgcn_mfma_f32_16x16x32_bf16(aqA[0], kf[nt][0], sAc[nt], 0, 0, 0);
                sAc[nt] = __builtin_amdgcn_mfma_f32_16x16x32_bf16(aqA[1], kf[nt][1], sAc[nt], 0, 0, 0);
            }
            sBc[nt] = __builtin_amdgcn_mfma_f32_16x16x32_bf16(aqB[0], kf[nt][0], sBc[nt], 0, 0, 0);
            sBc[nt] = __builtin_amdgcn_mfma_f32_16x16x32_bf16(aqB[1], kf[nt][1], sBc[nt], 0, 0, 0);
        }
    };
    auto mask_tile = [&](f32x4 (&s)[4]) {   // causal mask on the diagonal 64x64 tile
        #pragma unroll
        for (int nt = 0; nt < 4; ++nt) {
            const int col = nt * 16 + l16;
            #pragma unroll
            for (int r = 0; r < 4; ++r) {
                const int row = wid * 16 + quad * 4 + r;
                if (col > row) s[nt][r] = -1e30f;
            }
        }
    };

    // ================= pass 1: exact row max (K only, register-only) =================
    float mA[4] = {-1e30f, -1e30f, -1e30f, -1e30f};
    float mB[4] = {-1e30f, -1e30f, -1e30f, -1e30f};

    for (int j = 0; j <= jend; ++j) {
        const bool doA = (j <= x);
        short8 kf[4][2];
        #pragma unroll
        for (int nt = 0; nt < 4; ++nt)
            #pragma unroll
            for (int ks = 0; ks < 2; ++ks)
                kf[nt][ks] = *(const short8*)(Kfb + (size_t)(j * 64 + nt * 16) * 64 + ks * 32);
        f32x4 sAc[4] = {}, sBc[4] = {};
        qk_tiles(kf, sAc, sBc, doA);
        if (doA) {
            if (j == x) mask_tile(sAc);
            #pragma unroll
            for (int r = 0; r < 4; ++r)
                mA[r] = fmaxf(mA[r], fmaxf(fmaxf(sAc[0][r], sAc[1][r]), fmaxf(sAc[2][r], sAc[3][r])));
        }
        if (j == jend) mask_tile(sBc);
        #pragma unroll
        for (int r = 0; r < 4; ++r)
            mB[r] = fmaxf(mB[r], fmaxf(fmaxf(sBc[0][r], sBc[1][r]), fmaxf(sBc[2][r], sBc[3][r])));
    }
    float mLA[4], mLB[4];
    #pragma unroll
    for (int r = 0; r < 4; ++r) {
        mLA[r] = rowmax16(mA[r]) * LOG2E;
        mLB[r] = rowmax16(mB[r]) * LOG2E;
    }

    // ================= pass 2: fixed-max softmax + PV (no loop-carried chain) =================
    f32x4 oA[4] = {}, oB[4] = {};
    float lA[4] = {0.f, 0.f, 0.f, 0.f}, lB[4] = {0.f, 0.f, 0.f, 0.f};

    auto tile_exp = [&](f32x4 (&s)[4], const float (&mL)[4], float (&l_i)[4], bool msk,
                        unsigned short* Pw) {
        if (msk) mask_tile(s);
        #pragma unroll
        for (int nt = 0; nt < 4; ++nt) {
            const int col = nt * 16 + l16;
            #pragma unroll
            for (int r = 0; r < 4; ++r) {
                const float p = __builtin_exp2f(s[nt][r] * LOG2E - mL[r]);   // <= 1 always
                l_i[r] += p;
                Pw[(quad * 4 + r) * LDP + col] = f2bf(p);
            }
        }
    };

    unsigned short* PwA = &sP[wid][0][0];
    unsigned short* PwB = &sP[wid][1][0];

    for (int j = 0; j <= jend; ++j) {
        const bool doA = (j <= x);

        short8 kf[4][2], vf[4][2];
        #pragma unroll
        for (int nt = 0; nt < 4; ++nt)
            #pragma unroll
            for (int ks = 0; ks < 2; ++ks) {
                kf[nt][ks] = *(const short8*)(Kfb + (size_t)(j * 64 + nt * 16) * 64 + ks * 32);
                vf[nt][ks] = *(const short8*)(Vfb + (size_t)(nt * 16) * T_SEQ + j * 64 + ks * 32);
            }

        f32x4 sAc[4] = {}, sBc[4] = {};
        qk_tiles(kf, sAc, sBc, doA);

        if (doA) tile_exp(sAc, mLA, lA, j == x, PwA);
        tile_exp(sBc, mLB, lB, j == jend, PwB);
        asm volatile("s_waitcnt lgkmcnt(0)" ::: "memory");

        short8 pfA0 = {}, pfA1 = {}, pfB0, pfB1;
        if (doA) {
            pfA0 = *(const short8*)&PwA[l16 * LDP + quad * 8];
            pfA1 = *(const short8*)&PwA[l16 * LDP + 32 + quad * 8];
        }
        pfB0 = *(const short8*)&PwB[l16 * LDP + quad * 8];
        pfB1 = *(const short8*)&PwB[l16 * LDP + 32 + quad * 8];

        // O += P @ V  (V frags shared between tiles)
        #pragma unroll
        for (int dt = 0; dt < 4; ++dt) {
            if (doA) {
                oA[dt] = __builtin_amdgcn_mfma_f32_16x16x32_bf16(pfA0, vf[dt][0], oA[dt], 0, 0, 0);
                oA[dt] = __builtin_amdgcn_mfma_f32_16x16x32_bf16(pfA1, vf[dt][1], oA[dt], 0, 0, 0);
            }
            oB[dt] = __builtin_amdgcn_mfma_f32_16x16x32_bf16(pfB0, vf[dt][0], oB[dt], 0, 0, 0);
            oB[dt] = __builtin_amdgcn_mfma_f32_16x16x32_bf16(pfB1, vf[dt][1], oB[dt], 0, 0, 0);
        }
        // no __syncthreads anywhere: sP is strictly per-wave
    }

    // single cross-lane row-sum of the per-lane l partials
    #pragma unroll
    for (int r = 0; r < 4; ++r) {
        lA[r] = 1.f / rowsum16(lA[r]);
        lB[r] = 1.f / rowsum16(lB[r]);
    }

    // epilogue: normalize and write
    const int h = bh & 15, b = bh >> 4;
    #pragma unroll
    for (int dt = 0; dt < 4; ++dt)
        #pragma unroll
        for (int r = 0; r < 4; ++r) {
            const int rowA = qA * 64 + wid * 16 + quad * 4 + r;
            const int rowB = qB * 64 + wid * 16 + quad * 4 + r;
            const int col = h * 64 + dt * 16 + l16;
            Z[((size_t)b * T_SEQ + rowA) * D_MODEL + col] = f2bf(oA[dt][r] * lA[r]);
            Z[((size_t)b * T_SEQ + rowB) * D_MODEL + col] = f2bf(oB[dt][r] * lB[r]);
        }
}

// ---------------- launcher ----------------
extern "C" void kernel_launch(void* const* d_in, const int* in_sizes, int n_in,
                              void* d_out, int out_size, void* d_ws, size_t ws_size,
                              hipStream_t stream) {
    const float* x    = (const float*)d_in[0];
    const float* cosp = (const float*)d_in[1];
    const float* sinp = (const float*)d_in[2];
    const float* Wq   = (const float*)d_in[3];
    const float* Wk   = (const float*)d_in[4];
    const float* Wv   = (const float*)d_in[5];
    const float* Wo   = (const float*)d_in[6];

    char* w = (char*)d_ws;
    unsigned short* xb  = (unsigned short*)w; w += (size_t)M_TOT * D_MODEL * 2;    // 8 MB
    unsigned short* wt  = (unsigned short*)w; w += (size_t)4 * D_MODEL * D_MODEL * 2; // 8 MB (q,k,v,o)
    unsigned short* Qb  = (unsigned short*)w; w += (size_t)M_TOT * D_MODEL * 2;    // 8 MB
    unsigned short* Kb  = (unsigned short*)w; w += (size_t)M_TOT * D_MODEL * 2;
    unsigned short* Vtb = (unsigned short*)w; w += (size_t)M_TOT * D_MODEL * 2;    // [bh][d][t]
    unsigned short* Zb  = (unsigned short*)w; w += (size_t)M_TOT * D_MODEL * 2;

    convert_x_kernel<<<(M_TOT * D_MODEL) / 1024, 256, 0, stream>>>(x, xb);
    transpose_w_kernel<<<dim3(16, 16, 4), 256, 0, stream>>>(Wq, Wk, Wv, Wo, wt);

    // fused QKV projection; epilogue: z=0 Q(RoPE,*0.125), z=1 K(RoPE), z=2 V(transposed)
    gemm_kernel<4, 1><<<dim3(M_TOT / 128, D_MODEL / 128, 3), 256, 0, stream>>>(
        xb, wt, (void*)Qb, cosp, sinp);

    attn_kernel<<<dim3(16, 32), 256, 0, stream>>>(Qb, Kb, Vtb, Zb);

    // out projection -> fp32 d_out
    gemm_kernel<2, 0><<<dim3(M_TOT / 64, D_MODEL / 128, 1), 256, 0, stream>>>(
        Zb, wt + (size_t)3 * D_MODEL * D_MODEL, d_out, nullptr, nullptr);
}